// Round 9
// baseline (501.120 us; speedup 1.0000x reference)
//
#include <hip/hip_runtime.h>
#include <hip/hip_bf16.h>

// Problem constants
#define KN 2048
#define BB 4
#define DM 512
#define NH 8
#define HE 64
#define UP 40
#define NBH 32          // B*H
#define NROWS 8192      // KN*B
#define MiB(x) ((size_t)(x) << 20)

// ---------------------------------------------------------------------------
// Tiled f32 GEMM:  C[m,o] = (sum_k A[m,k]*W[o,k] + bias[o]) * scale
// tile 128x64, K-step 32, 256 threads, 8x4 register blocking per thread
// ---------------------------------------------------------------------------
__global__ __launch_bounds__(256) void gemm_bt(
    const float* __restrict__ A, const float* __restrict__ W,
    const float* __restrict__ bias, float scale, float* __restrict__ C) {
  __shared__ float As[32][132];  // [k][m], padded
  __shared__ float Ws[32][68];   // [k][o]
  const int m0 = blockIdx.y * 128;
  const int o0 = blockIdx.x * 64;
  const int tid = threadIdx.x;
  const int tx = tid & 15;
  const int ty = tid >> 4;
  float acc[8][4] = {};

  for (int k0 = 0; k0 < 512; k0 += 32) {
#pragma unroll
    for (int i = 0; i < 4; ++i) {
      int flat = tid + i * 256;      // 0..1023
      int r = flat >> 3;             // 0..127
      int c4 = flat & 7;
      float4 av = *(const float4*)(A + (size_t)(m0 + r) * 512 + k0 + c4 * 4);
      As[c4 * 4 + 0][r] = av.x; As[c4 * 4 + 1][r] = av.y;
      As[c4 * 4 + 2][r] = av.z; As[c4 * 4 + 3][r] = av.w;
    }
#pragma unroll
    for (int i = 0; i < 2; ++i) {
      int flat = tid + i * 256;      // 0..511
      int r = flat >> 3;             // 0..63
      int c4 = flat & 7;
      float4 wv = *(const float4*)(W + (size_t)(o0 + r) * 512 + k0 + c4 * 4);
      Ws[c4 * 4 + 0][r] = wv.x; Ws[c4 * 4 + 1][r] = wv.y;
      Ws[c4 * 4 + 2][r] = wv.z; Ws[c4 * 4 + 3][r] = wv.w;
    }
    __syncthreads();
#pragma unroll
    for (int kk = 0; kk < 32; ++kk) {
      float a_[8], w_[4];
#pragma unroll
      for (int i = 0; i < 8; ++i) a_[i] = As[kk][ty * 8 + i];
#pragma unroll
      for (int j = 0; j < 4; ++j) w_[j] = Ws[kk][tx * 4 + j];
#pragma unroll
      for (int i = 0; i < 8; ++i)
#pragma unroll
        for (int j = 0; j < 4; ++j)
          acc[i][j] = fmaf(a_[i], w_[j], acc[i][j]);
    }
    __syncthreads();
  }

#pragma unroll
  for (int i = 0; i < 8; ++i) {
    int m = m0 + ty * 8 + i;
#pragma unroll
    for (int j = 0; j < 4; ++j) {
      int o = o0 + tx * 4 + j;
      C[(size_t)m * 512 + o] = (acc[i][j] + bias[o]) * scale;
    }
  }
}

// ---------------------------------------------------------------------------
// Transpose K into Kt[bh][e][n] for coalesced attention score reads.
// ---------------------------------------------------------------------------
__global__ __launch_bounds__(256) void transposeK_kernel(
    const float* __restrict__ K, float* __restrict__ Kt) {
  const int bh = blockIdx.x & 31;
  const int nt = blockIdx.x >> 5;       // 0..15
  const int b = bh >> 3, h = bh & 7;
  const int n0 = nt * 128;
  const int tid = threadIdx.x;
  __shared__ float T[128][65];

#pragma unroll
  for (int i = 0; i < 8; ++i) {
    int flat = tid + i * 256;           // 0..2047
    int r = flat >> 4;                  // 0..127
    int c4 = flat & 15;                 // 0..15
    float4 v = *(const float4*)(K + (((size_t)(n0 + r) * 4 + b) * 8 + h) * 64 + c4 * 4);
    T[r][c4 * 4 + 0] = v.x; T[r][c4 * 4 + 1] = v.y;
    T[r][c4 * 4 + 2] = v.z; T[r][c4 * 4 + 3] = v.w;
  }
  __syncthreads();

  const int nl = tid & 127;             // 0..127
  const int eg = tid >> 7;              // 0..1
#pragma unroll
  for (int e = eg * 32; e < eg * 32 + 32; ++e)
    Kt[((size_t)bh * 64 + e) * 2048 + n0 + nl] = T[nl][e];
}

// ---------------------------------------------------------------------------
// M scores, split over samples, XCD-local over bh.
// grid 1024: blockIdx = X*32 + bh  (so blockIdx%8 == bh%8 -> 4 bh per XCD,
// K working set 2 MiB per XCD L2).  X = spart*8 + nchunk.
// Thread computes partial max/sum over samples [spart*10, spart*10+10)
// for (bh, n = nchunk*256 + tid).
// ---------------------------------------------------------------------------
__global__ __launch_bounds__(256) void mscore_part(
    const float* __restrict__ Q, const float* __restrict__ K,
    const int* __restrict__ idx, float* __restrict__ Mmax,
    float* __restrict__ Msum) {
  const int bh = blockIdx.x & 31;
  const int X  = blockIdx.x >> 5;       // 0..31
  const int spart = X >> 3;             // 0..3
  const int nchunk = X & 7;             // 0..7
  const int n = nchunk * 256 + threadIdx.x;
  const int b = bh >> 3, h = bh & 7;

  float q[64];
  const float4* qrow = (const float4*)(Q + (((size_t)n * 4 + b) * 8 + h) * 64);
#pragma unroll
  for (int e4 = 0; e4 < 16; ++e4) {
    float4 v = qrow[e4];
    q[4 * e4 + 0] = v.x; q[4 * e4 + 1] = v.y;
    q[4 * e4 + 2] = v.z; q[4 * e4 + 3] = v.w;
  }

  float mx = -INFINITY, sm = 0.f;
  const int s0 = spart * 10;
#pragma unroll
  for (int s = s0; s < s0 + 10; ++s) {
    const int kn = idx[n * UP + s];
    const float4* kr = (const float4*)(K + (((size_t)kn * 4 + b) * 8 + h) * 64);
    float d = 0.f;
#pragma unroll
    for (int e4 = 0; e4 < 16; ++e4) {
      float4 kv = kr[e4];
      d += q[4 * e4 + 0] * kv.x + q[4 * e4 + 1] * kv.y +
           q[4 * e4 + 2] * kv.z + q[4 * e4 + 3] * kv.w;
    }
    mx = fmaxf(mx, d);
    sm += d;
  }
  const size_t o = (size_t)spart * 65536 + (size_t)bh * 2048 + n;
  Mmax[o] = mx;
  Msum[o] = sm;
}

__global__ __launch_bounds__(256) void mscore_combine(
    const float* __restrict__ Mmax, const float* __restrict__ Msum,
    float* __restrict__ Mout) {
  const int t = blockIdx.x * 256 + threadIdx.x;   // [0, 65536)
  float mx = Mmax[t];
  float sm = Msum[t];
#pragma unroll
  for (int p = 1; p < 4; ++p) {
    mx = fmaxf(mx, Mmax[(size_t)p * 65536 + t]);
    sm += Msum[(size_t)p * 65536 + t];
  }
  Mout[t] = mx - sm * (1.0f / (float)KN);
}

// ---------------------------------------------------------------------------
// top-40 per (b,h): iterative argmax, lowest-index tiebreak
// ---------------------------------------------------------------------------
__global__ __launch_bounds__(256) void topk_kernel(
    const float* __restrict__ M, int* __restrict__ Mtop) {
  const int bh = blockIdx.x;
  __shared__ float vals[2048];
  __shared__ float rv[256];
  __shared__ int ri[256];
  const float* Mrow = M + (size_t)bh * 2048;
  for (int i = threadIdx.x; i < 2048; i += 256) vals[i] = Mrow[i];
  __syncthreads();
  for (int it = 0; it < UP; ++it) {
    float bv = -INFINITY; int bi = 0x7fffffff;
    for (int i = threadIdx.x; i < 2048; i += 256) {
      float v = vals[i];
      if (v > bv) { bv = v; bi = i; }
    }
    rv[threadIdx.x] = bv; ri[threadIdx.x] = bi;
    __syncthreads();
    for (int st = 128; st; st >>= 1) {
      if (threadIdx.x < st) {
        float ov = rv[threadIdx.x + st]; int oi = ri[threadIdx.x + st];
        float cv = rv[threadIdx.x];      int ci = ri[threadIdx.x];
        if (ov > cv || (ov == cv && oi < ci)) { rv[threadIdx.x] = ov; ri[threadIdx.x] = oi; }
      }
      __syncthreads();
    }
    if (threadIdx.x == 0) { Mtop[bh * UP + it] = ri[0]; vals[ri[0]] = -INFINITY; }
    __syncthreads();
  }
}

// ---------------------------------------------------------------------------
// mean of V: two-phase coalesced column-sum (V is a [2048][2048] matrix).
// ---------------------------------------------------------------------------
__global__ __launch_bounds__(256) void meanv_part(
    const float* __restrict__ V, float* __restrict__ part) {
  const int rc = blockIdx.x >> 3;      // 0..31 (row chunk of 64)
  const int cc = blockIdx.x & 7;       // 0..7  (col chunk of 256)
  const int c = cc * 256 + threadIdx.x;
  const float* p = V + (size_t)rc * 64 * 2048 + c;
  float acc = 0.f;
#pragma unroll 8
  for (int i = 0; i < 64; ++i) acc += p[(size_t)i * 2048];
  part[(size_t)rc * 2048 + c] = acc;
}

__global__ __launch_bounds__(256) void meanv_final(
    const float* __restrict__ part, float* __restrict__ mnV) {
  const int c = blockIdx.x * 256 + threadIdx.x;   // 8 blocks
  float acc = 0.f;
#pragma unroll
  for (int r = 0; r < 32; ++r) acc += part[(size_t)r * 2048 + c];
  mnV[c] = acc * (1.0f / (float)KN);
}

// ---------------------------------------------------------------------------
// Batched attention: one block per (bh, group of 5 queries), 256 blocks.
// ---------------------------------------------------------------------------
#define QG 5   // queries per block
__global__ __launch_bounds__(256) void attn_kernel(
    const float* __restrict__ Q, const float* __restrict__ Kt,
    const float* __restrict__ V, const int* __restrict__ Mtop,
    float* __restrict__ upd) {
  const int bh = blockIdx.x >> 3;
  const int g  = blockIdx.x & 7;        // query group
  const int b = bh >> 3, h = bh & 7;
  const int tid = threadIdx.x;
  const int wv = tid >> 6, lane = tid & 63;

  __shared__ float qs[QG][64];
  __shared__ float p[QG][2048];
  __shared__ float redm[QG][4];
  __shared__ float reds[QG][4];
  __shared__ float pvp[4][QG][64];

  // load 5 selected q rows
  for (int i = tid; i < QG * 64; i += 256) {
    int q = i >> 6, e = i & 63;
    int nq = Mtop[bh * UP + g * QG + q];
    qs[q][e] = Q[(((size_t)nq * 4 + b) * 8 + h) * 64 + e];
  }
  __syncthreads();

  // phase 1: scores. thread t owns n = j*1024 + t*4 + {0..3}, j in {0,1}
  const float* ktb = Kt + (size_t)bh * 64 * 2048;
  float sc[QG][8];
#pragma unroll
  for (int j = 0; j < 2; ++j) {
    const int nb = j * 1024 + tid * 4;
    float d[QG][4] = {};
    for (int e = 0; e < 64; ++e) {
      float4 kv = *(const float4*)(ktb + (size_t)e * 2048 + nb);
#pragma unroll
      for (int q = 0; q < QG; ++q) {
        float qe = qs[q][e];
        d[q][0] = fmaf(qe, kv.x, d[q][0]);
        d[q][1] = fmaf(qe, kv.y, d[q][1]);
        d[q][2] = fmaf(qe, kv.z, d[q][2]);
        d[q][3] = fmaf(qe, kv.w, d[q][3]);
      }
    }
#pragma unroll
    for (int q = 0; q < QG; ++q)
#pragma unroll
      for (int i = 0; i < 4; ++i) sc[q][j * 4 + i] = d[q][i];
  }

  // phase 2a: block max per q
#pragma unroll
  for (int q = 0; q < QG; ++q) {
    float m_ = sc[q][0];
#pragma unroll
    for (int j = 1; j < 8; ++j) m_ = fmaxf(m_, sc[q][j]);
#pragma unroll
    for (int off = 1; off < 64; off <<= 1)
      m_ = fmaxf(m_, __shfl_xor(m_, off));
    if (lane == 0) redm[q][wv] = m_;
  }
  __syncthreads();
  float gmax[QG];
#pragma unroll
  for (int q = 0; q < QG; ++q)
    gmax[q] = fmaxf(fmaxf(redm[q][0], redm[q][1]),
                    fmaxf(redm[q][2], redm[q][3]));

  // phase 2b: exp, store p (float4), block sum per q
  float lsum[QG] = {};
#pragma unroll
  for (int j = 0; j < 2; ++j) {
#pragma unroll
    for (int q = 0; q < QG; ++q) {
      float4 pe;
      pe.x = __expf(sc[q][j * 4 + 0] - gmax[q]);
      pe.y = __expf(sc[q][j * 4 + 1] - gmax[q]);
      pe.z = __expf(sc[q][j * 4 + 2] - gmax[q]);
      pe.w = __expf(sc[q][j * 4 + 3] - gmax[q]);
      *(float4*)(&p[q][j * 1024 + tid * 4]) = pe;
      lsum[q] += pe.x + pe.y + pe.z + pe.w;
    }
  }
#pragma unroll
  for (int q = 0; q < QG; ++q) {
    float s_ = lsum[q];
#pragma unroll
    for (int off = 1; off < 64; off <<= 1)
      s_ += __shfl_xor(s_, off);
    if (lane == 0) reds[q][wv] = s_;
  }
  __syncthreads();
  float denom[QG];
#pragma unroll
  for (int q = 0; q < QG; ++q)
    denom[q] = reds[q][0] + reds[q][1] + reds[q][2] + reds[q][3];

  // phase 3: PV. wave wv handles n in [wv*512, wv*512+512), lane = e.
  float acc[QG] = {};
  for (int n = wv * 512; n < wv * 512 + 512; ++n) {
    float v = V[(((size_t)n * 4 + b) * 8 + h) * 64 + lane];
#pragma unroll
    for (int q = 0; q < QG; ++q) acc[q] = fmaf(p[q][n], v, acc[q]);
  }
#pragma unroll
  for (int q = 0; q < QG; ++q) pvp[wv][q][lane] = acc[q];
  __syncthreads();

  for (int i = tid; i < QG * 64; i += 256) {
    int q = i >> 6, e = i & 63;
    float r = (pvp[0][q][e] + pvp[1][q][e] + pvp[2][q][e] + pvp[3][q][e]) /
              denom[q];
    upd[(size_t)(bh * UP + g * QG + q) * 64 + e] = r;
  }
}

// ---------------------------------------------------------------------------
// ctx fill: ctx[(b*2048+n)*512 + d] = meanV[b*512 + d]
// ---------------------------------------------------------------------------
__global__ void fillctx_kernel(const float* __restrict__ meanV,
                               float* __restrict__ ctx) {
  size_t i = ((size_t)blockIdx.x * 256 + threadIdx.x) * 4;
  int d = (int)(i & 511);
  int b = (int)(i >> 20);
  float4 v = *(const float4*)(meanV + (b << 9) + d);
  *(float4*)(ctx + i) = v;
}

// ---------------------------------------------------------------------------
// scatter selected rows
// ---------------------------------------------------------------------------
__global__ void scatter_kernel(const float* __restrict__ upd,
                               const int* __restrict__ Mtop,
                               float* __restrict__ ctx) {
  const int blk = blockIdx.x;   // bh*40 + s
  const int bh = blk / UP;
  const int b = bh >> 3, h = bh & 7;
  const int n = Mtop[blk];
  ctx[((size_t)(b * 2048 + n)) * 512 + h * 64 + threadIdx.x] =
      upd[(size_t)blk * 64 + threadIdx.x];
}

// ---------------------------------------------------------------------------
// Workspace layout (67 MiB used; ws >= 113 MiB proven in R4):
//   [0,       256K)    Mbuf   32*2048 f32
//   [256K,    576K)    upd    1280*64 f32
//   [589824,  598016)  mnV    32*64 f32
//   [598016,  603136)  Mtop   1280 i32
//   [634880,  897024)  vpart  32*2048 f32
//   [1M, 17M) Q (ctx alias)   [17M, 33M) K   [33M, 49M) V   [49M, 65M) Kt
//   [65M, 66M) Mmax 4*65536 f32   [66M, 67M) Msum 4*65536 f32
// ---------------------------------------------------------------------------
extern "C" void kernel_launch(void* const* d_in, const int* in_sizes, int n_in,
                              void* d_out, int out_size, void* d_ws,
                              size_t ws_size, hipStream_t stream) {
  const float* query = (const float*)d_in[0];
  const float* key   = (const float*)d_in[1];
  const float* value = (const float*)d_in[2];
  const int*   idxs  = (const int*)d_in[3];
  const float* Wq = (const float*)d_in[4];
  const float* bq = (const float*)d_in[5];
  const float* Wk = (const float*)d_in[6];
  const float* bk = (const float*)d_in[7];
  const float* Wv = (const float*)d_in[8];
  const float* bv = (const float*)d_in[9];
  const float* Wo = (const float*)d_in[10];
  const float* bo = (const float*)d_in[11];
  float* out = (float*)d_out;    // reference output dtype is float32

  char* ws = (char*)d_ws;
  float* Mbuf  = (float*)(ws + 0);
  float* upd   = (float*)(ws + 262144);
  float* mnV   = (float*)(ws + 589824);
  int*   Mtop  = (int*)  (ws + 598016);
  float* vpart = (float*)(ws + 634880);
  float* Q     = (float*)(ws + MiB(1));
  float* K     = (float*)(ws + MiB(17));
  float* V     = (float*)(ws + MiB(33));
  float* Kt    = (float*)(ws + MiB(49));
  float* Mmax  = (float*)(ws + MiB(65));
  float* Msum  = (float*)(ws + MiB(66));
  float* ctx   = Q;   // Q dead after attn_kernel; ctx written afterwards

  dim3 g(8, 64), blk(256);
  gemm_bt<<<g, blk, 0, stream>>>(query, Wq, bq, 0.125f, Q);
  gemm_bt<<<g, blk, 0, stream>>>(key,   Wk, bk, 1.0f,   K);
  gemm_bt<<<g, blk, 0, stream>>>(value, Wv, bv, 1.0f,   V);

  transposeK_kernel<<<512, 256, 0, stream>>>(K, Kt);

  mscore_part<<<1024, 256, 0, stream>>>(Q, K, idxs, Mmax, Msum);
  mscore_combine<<<256, 256, 0, stream>>>(Mmax, Msum, Mbuf);
  topk_kernel<<<NBH, 256, 0, stream>>>(Mbuf, Mtop);
  meanv_part<<<256, 256, 0, stream>>>(V, vpart);
  meanv_final<<<8, 256, 0, stream>>>(vpart, mnV);
  attn_kernel<<<NBH * 8, 256, 0, stream>>>(Q, Kt, V, Mtop, upd);

  fillctx_kernel<<<4096, 256, 0, stream>>>(mnV, ctx);
  scatter_kernel<<<NBH * UP, 64, 0, stream>>>(upd, Mtop, ctx);

  gemm_bt<<<g, blk, 0, stream>>>(ctx, Wo, bo, 1.0f, out);
}

// Round 10
// 408.224 us; speedup vs baseline: 1.2276x; 1.2276x over previous
//
#include <hip/hip_runtime.h>
#include <hip/hip_bf16.h>

// Problem constants
#define KN 2048
#define BB 4
#define DM 512
#define NH 8
#define HE 64
#define UP 40
#define NBH 32          // B*H
#define NROWS 8192      // KN*B
#define MiB(x) ((size_t)(x) << 20)

// ---------------------------------------------------------------------------
// Tiled f32 GEMM:  C[m,o] = (sum_k A[m,k]*W[o,k] + bias[o]) * scale
// tile 128x64, K-step 32, 256 threads, 8x4 register blocking per thread
// ---------------------------------------------------------------------------
__global__ __launch_bounds__(256) void gemm_bt(
    const float* __restrict__ A, const float* __restrict__ W,
    const float* __restrict__ bias, float scale, float* __restrict__ C) {
  __shared__ float As[32][132];  // [k][m], padded
  __shared__ float Ws[32][68];   // [k][o]
  const int m0 = blockIdx.y * 128;
  const int o0 = blockIdx.x * 64;
  const int tid = threadIdx.x;
  const int tx = tid & 15;
  const int ty = tid >> 4;
  float acc[8][4] = {};

  for (int k0 = 0; k0 < 512; k0 += 32) {
#pragma unroll
    for (int i = 0; i < 4; ++i) {
      int flat = tid + i * 256;      // 0..1023
      int r = flat >> 3;             // 0..127
      int c4 = flat & 7;
      float4 av = *(const float4*)(A + (size_t)(m0 + r) * 512 + k0 + c4 * 4);
      As[c4 * 4 + 0][r] = av.x; As[c4 * 4 + 1][r] = av.y;
      As[c4 * 4 + 2][r] = av.z; As[c4 * 4 + 3][r] = av.w;
    }
#pragma unroll
    for (int i = 0; i < 2; ++i) {
      int flat = tid + i * 256;      // 0..511
      int r = flat >> 3;             // 0..63
      int c4 = flat & 7;
      float4 wv = *(const float4*)(W + (size_t)(o0 + r) * 512 + k0 + c4 * 4);
      Ws[c4 * 4 + 0][r] = wv.x; Ws[c4 * 4 + 1][r] = wv.y;
      Ws[c4 * 4 + 2][r] = wv.z; Ws[c4 * 4 + 3][r] = wv.w;
    }
    __syncthreads();
#pragma unroll
    for (int kk = 0; kk < 32; ++kk) {
      float a_[8], w_[4];
#pragma unroll
      for (int i = 0; i < 8; ++i) a_[i] = As[kk][ty * 8 + i];
#pragma unroll
      for (int j = 0; j < 4; ++j) w_[j] = Ws[kk][tx * 4 + j];
#pragma unroll
      for (int i = 0; i < 8; ++i)
#pragma unroll
        for (int j = 0; j < 4; ++j)
          acc[i][j] = fmaf(a_[i], w_[j], acc[i][j]);
    }
    __syncthreads();
  }

#pragma unroll
  for (int i = 0; i < 8; ++i) {
    int m = m0 + ty * 8 + i;
#pragma unroll
    for (int j = 0; j < 4; ++j) {
      int o = o0 + tx * 4 + j;
      C[(size_t)m * 512 + o] = (acc[i][j] + bias[o]) * scale;
    }
  }
}

// ---------------------------------------------------------------------------
// Transpose K into Kt[bh][e][n] for coalesced attention score reads.
// ---------------------------------------------------------------------------
__global__ __launch_bounds__(256) void transposeK_kernel(
    const float* __restrict__ K, float* __restrict__ Kt) {
  const int bh = blockIdx.x & 31;
  const int nt = blockIdx.x >> 5;       // 0..15
  const int b = bh >> 3, h = bh & 7;
  const int n0 = nt * 128;
  const int tid = threadIdx.x;
  __shared__ float T[128][65];

#pragma unroll
  for (int i = 0; i < 8; ++i) {
    int flat = tid + i * 256;           // 0..2047
    int r = flat >> 4;                  // 0..127
    int c4 = flat & 15;                 // 0..15
    float4 v = *(const float4*)(K + (((size_t)(n0 + r) * 4 + b) * 8 + h) * 64 + c4 * 4);
    T[r][c4 * 4 + 0] = v.x; T[r][c4 * 4 + 1] = v.y;
    T[r][c4 * 4 + 2] = v.z; T[r][c4 * 4 + 3] = v.w;
  }
  __syncthreads();

  const int nl = tid & 127;             // 0..127
  const int eg = tid >> 7;              // 0..1
#pragma unroll
  for (int e = eg * 32; e < eg * 32 + 32; ++e)
    Kt[((size_t)bh * 64 + e) * 2048 + n0 + nl] = T[nl][e];
}

// ---------------------------------------------------------------------------
// M scores, wave-cooperative gather. One wave per (bh, n).
// 16 lanes cover one K row (16 x float4 = 256 B, 4 fully-used cache lines),
// 4 sample-rows per wave instruction -> no gather line-amplification.
// blockIdx = c*32 + bh keeps blockIdx%8 == bh%8 (XCD-local K slice, 2 MiB/L2).
// Reduction: 4-step shfl_xor within 16-lane group (dot), running max/sum per
// group over its 10 samples, then 2-step cross-group shfl combine.
// ---------------------------------------------------------------------------
__global__ __launch_bounds__(256) void mscore_kernel(
    const float* __restrict__ Q, const float* __restrict__ K,
    const int* __restrict__ idx, float* __restrict__ Mout) {
  const int bh = blockIdx.x & 31;
  const int c  = blockIdx.x >> 5;        // 0..511
  const int wv = threadIdx.x >> 6;       // 0..3
  const int lane = threadIdx.x & 63;
  const int n = c * 4 + wv;
  const int b = bh >> 3, h = bh & 7;
  const int g = lane >> 4;               // sample group 0..3
  const int e16 = lane & 15;             // element chunk within row

  const float4 qv = *(const float4*)(Q + (((size_t)n * 4 + b) * 8 + h) * 64 + e16 * 4);

  float mx = -INFINITY, sm = 0.f;
#pragma unroll
  for (int it = 0; it < 10; ++it) {
    const int s = it * 4 + g;
    const int kn = idx[n * UP + s];
    const float4 kv = *(const float4*)(K + (((size_t)kn * 4 + b) * 8 + h) * 64 + e16 * 4);
    float d = qv.x * kv.x + qv.y * kv.y + qv.z * kv.z + qv.w * kv.w;
    d += __shfl_xor(d, 1);
    d += __shfl_xor(d, 2);
    d += __shfl_xor(d, 4);
    d += __shfl_xor(d, 8);               // all 16 lanes of group hold the dot
    mx = fmaxf(mx, d);
    sm += d;
  }
  // combine the 4 groups
  mx = fmaxf(mx, __shfl_xor(mx, 16));
  mx = fmaxf(mx, __shfl_xor(mx, 32));
  sm += __shfl_xor(sm, 16);
  sm += __shfl_xor(sm, 32);
  if (lane == 0) Mout[(size_t)bh * 2048 + n] = mx - sm * (1.0f / (float)KN);
}

// ---------------------------------------------------------------------------
// top-40 per (b,h): iterative argmax, lowest-index tiebreak
// ---------------------------------------------------------------------------
__global__ __launch_bounds__(256) void topk_kernel(
    const float* __restrict__ M, int* __restrict__ Mtop) {
  const int bh = blockIdx.x;
  __shared__ float vals[2048];
  __shared__ float rv[256];
  __shared__ int ri[256];
  const float* Mrow = M + (size_t)bh * 2048;
  for (int i = threadIdx.x; i < 2048; i += 256) vals[i] = Mrow[i];
  __syncthreads();
  for (int it = 0; it < UP; ++it) {
    float bv = -INFINITY; int bi = 0x7fffffff;
    for (int i = threadIdx.x; i < 2048; i += 256) {
      float v = vals[i];
      if (v > bv) { bv = v; bi = i; }
    }
    rv[threadIdx.x] = bv; ri[threadIdx.x] = bi;
    __syncthreads();
    for (int st = 128; st; st >>= 1) {
      if (threadIdx.x < st) {
        float ov = rv[threadIdx.x + st]; int oi = ri[threadIdx.x + st];
        float cv = rv[threadIdx.x];      int ci = ri[threadIdx.x];
        if (ov > cv || (ov == cv && oi < ci)) { rv[threadIdx.x] = ov; ri[threadIdx.x] = oi; }
      }
      __syncthreads();
    }
    if (threadIdx.x == 0) { Mtop[bh * UP + it] = ri[0]; vals[ri[0]] = -INFINITY; }
    __syncthreads();
  }
}

// ---------------------------------------------------------------------------
// mean of V: two-phase coalesced column-sum (V is a [2048][2048] matrix).
// ---------------------------------------------------------------------------
__global__ __launch_bounds__(256) void meanv_part(
    const float* __restrict__ V, float* __restrict__ part) {
  const int rc = blockIdx.x >> 3;      // 0..31 (row chunk of 64)
  const int cc = blockIdx.x & 7;       // 0..7  (col chunk of 256)
  const int c = cc * 256 + threadIdx.x;
  const float* p = V + (size_t)rc * 64 * 2048 + c;
  float acc = 0.f;
#pragma unroll 8
  for (int i = 0; i < 64; ++i) acc += p[(size_t)i * 2048];
  part[(size_t)rc * 2048 + c] = acc;
}

__global__ __launch_bounds__(256) void meanv_final(
    const float* __restrict__ part, float* __restrict__ mnV) {
  const int c = blockIdx.x * 256 + threadIdx.x;   // 8 blocks
  float acc = 0.f;
#pragma unroll
  for (int r = 0; r < 32; ++r) acc += part[(size_t)r * 2048 + c];
  mnV[c] = acc * (1.0f / (float)KN);
}

// ---------------------------------------------------------------------------
// Batched attention: one block per (bh, group of 5 queries), 256 blocks.
// ---------------------------------------------------------------------------
#define QG 5   // queries per block
__global__ __launch_bounds__(256) void attn_kernel(
    const float* __restrict__ Q, const float* __restrict__ Kt,
    const float* __restrict__ V, const int* __restrict__ Mtop,
    float* __restrict__ upd) {
  const int bh = blockIdx.x >> 3;
  const int g  = blockIdx.x & 7;        // query group
  const int b = bh >> 3, h = bh & 7;
  const int tid = threadIdx.x;
  const int wv = tid >> 6, lane = tid & 63;

  __shared__ float qs[QG][64];
  __shared__ float p[QG][2048];
  __shared__ float redm[QG][4];
  __shared__ float reds[QG][4];
  __shared__ float pvp[4][QG][64];

  // load 5 selected q rows
  for (int i = tid; i < QG * 64; i += 256) {
    int q = i >> 6, e = i & 63;
    int nq = Mtop[bh * UP + g * QG + q];
    qs[q][e] = Q[(((size_t)nq * 4 + b) * 8 + h) * 64 + e];
  }
  __syncthreads();

  // phase 1: scores. thread t owns n = j*1024 + t*4 + {0..3}, j in {0,1}
  const float* ktb = Kt + (size_t)bh * 64 * 2048;
  float sc[QG][8];
#pragma unroll
  for (int j = 0; j < 2; ++j) {
    const int nb = j * 1024 + tid * 4;
    float d[QG][4] = {};
    for (int e = 0; e < 64; ++e) {
      float4 kv = *(const float4*)(ktb + (size_t)e * 2048 + nb);
#pragma unroll
      for (int q = 0; q < QG; ++q) {
        float qe = qs[q][e];
        d[q][0] = fmaf(qe, kv.x, d[q][0]);
        d[q][1] = fmaf(qe, kv.y, d[q][1]);
        d[q][2] = fmaf(qe, kv.z, d[q][2]);
        d[q][3] = fmaf(qe, kv.w, d[q][3]);
      }
    }
#pragma unroll
    for (int q = 0; q < QG; ++q)
#pragma unroll
      for (int i = 0; i < 4; ++i) sc[q][j * 4 + i] = d[q][i];
  }

  // phase 2a: block max per q
#pragma unroll
  for (int q = 0; q < QG; ++q) {
    float m_ = sc[q][0];
#pragma unroll
    for (int j = 1; j < 8; ++j) m_ = fmaxf(m_, sc[q][j]);
#pragma unroll
    for (int off = 1; off < 64; off <<= 1)
      m_ = fmaxf(m_, __shfl_xor(m_, off));
    if (lane == 0) redm[q][wv] = m_;
  }
  __syncthreads();
  float gmax[QG];
#pragma unroll
  for (int q = 0; q < QG; ++q)
    gmax[q] = fmaxf(fmaxf(redm[q][0], redm[q][1]),
                    fmaxf(redm[q][2], redm[q][3]));

  // phase 2b: exp, store p (float4), block sum per q
  float lsum[QG] = {};
#pragma unroll
  for (int j = 0; j < 2; ++j) {
#pragma unroll
    for (int q = 0; q < QG; ++q) {
      float4 pe;
      pe.x = __expf(sc[q][j * 4 + 0] - gmax[q]);
      pe.y = __expf(sc[q][j * 4 + 1] - gmax[q]);
      pe.z = __expf(sc[q][j * 4 + 2] - gmax[q]);
      pe.w = __expf(sc[q][j * 4 + 3] - gmax[q]);
      *(float4*)(&p[q][j * 1024 + tid * 4]) = pe;
      lsum[q] += pe.x + pe.y + pe.z + pe.w;
    }
  }
#pragma unroll
  for (int q = 0; q < QG; ++q) {
    float s_ = lsum[q];
#pragma unroll
    for (int off = 1; off < 64; off <<= 1)
      s_ += __shfl_xor(s_, off);
    if (lane == 0) reds[q][wv] = s_;
  }
  __syncthreads();
  float denom[QG];
#pragma unroll
  for (int q = 0; q < QG; ++q)
    denom[q] = reds[q][0] + reds[q][1] + reds[q][2] + reds[q][3];

  // phase 3: PV. wave wv handles n in [wv*512, wv*512+512), lane = e.
  float acc[QG] = {};
  for (int n = wv * 512; n < wv * 512 + 512; ++n) {
    float v = V[(((size_t)n * 4 + b) * 8 + h) * 64 + lane];
#pragma unroll
    for (int q = 0; q < QG; ++q) acc[q] = fmaf(p[q][n], v, acc[q]);
  }
#pragma unroll
  for (int q = 0; q < QG; ++q) pvp[wv][q][lane] = acc[q];
  __syncthreads();

  for (int i = tid; i < QG * 64; i += 256) {
    int q = i >> 6, e = i & 63;
    float r = (pvp[0][q][e] + pvp[1][q][e] + pvp[2][q][e] + pvp[3][q][e]) /
              denom[q];
    upd[(size_t)(bh * UP + g * QG + q) * 64 + e] = r;
  }
}

// ---------------------------------------------------------------------------
// ctx fill: ctx[(b*2048+n)*512 + d] = meanV[b*512 + d]
// ---------------------------------------------------------------------------
__global__ void fillctx_kernel(const float* __restrict__ meanV,
                               float* __restrict__ ctx) {
  size_t i = ((size_t)blockIdx.x * 256 + threadIdx.x) * 4;
  int d = (int)(i & 511);
  int b = (int)(i >> 20);
  float4 v = *(const float4*)(meanV + (b << 9) + d);
  *(float4*)(ctx + i) = v;
}

// ---------------------------------------------------------------------------
// scatter selected rows
// ---------------------------------------------------------------------------
__global__ void scatter_kernel(const float* __restrict__ upd,
                               const int* __restrict__ Mtop,
                               float* __restrict__ ctx) {
  const int blk = blockIdx.x;   // bh*40 + s
  const int bh = blk / UP;
  const int b = bh >> 3, h = bh & 7;
  const int n = Mtop[blk];
  ctx[((size_t)(b * 2048 + n)) * 512 + h * 64 + threadIdx.x] =
      upd[(size_t)blk * 64 + threadIdx.x];
}

// ---------------------------------------------------------------------------
// Workspace layout (65 MiB used; ws >= 113 MiB proven in R4):
//   [0,       256K)    Mbuf   32*2048 f32
//   [256K,    576K)    upd    1280*64 f32
//   [589824,  598016)  mnV    32*64 f32
//   [598016,  603136)  Mtop   1280 i32
//   [634880,  897024)  vpart  32*2048 f32
//   [1M, 17M) Q (ctx alias)   [17M, 33M) K   [33M, 49M) V   [49M, 65M) Kt
// ---------------------------------------------------------------------------
extern "C" void kernel_launch(void* const* d_in, const int* in_sizes, int n_in,
                              void* d_out, int out_size, void* d_ws,
                              size_t ws_size, hipStream_t stream) {
  const float* query = (const float*)d_in[0];
  const float* key   = (const float*)d_in[1];
  const float* value = (const float*)d_in[2];
  const int*   idxs  = (const int*)d_in[3];
  const float* Wq = (const float*)d_in[4];
  const float* bq = (const float*)d_in[5];
  const float* Wk = (const float*)d_in[6];
  const float* bk = (const float*)d_in[7];
  const float* Wv = (const float*)d_in[8];
  const float* bv = (const float*)d_in[9];
  const float* Wo = (const float*)d_in[10];
  const float* bo = (const float*)d_in[11];
  float* out = (float*)d_out;    // reference output dtype is float32

  char* ws = (char*)d_ws;
  float* Mbuf  = (float*)(ws + 0);
  float* upd   = (float*)(ws + 262144);
  float* mnV   = (float*)(ws + 589824);
  int*   Mtop  = (int*)  (ws + 598016);
  float* vpart = (float*)(ws + 634880);
  float* Q     = (float*)(ws + MiB(1));
  float* K     = (float*)(ws + MiB(17));
  float* V     = (float*)(ws + MiB(33));
  float* Kt    = (float*)(ws + MiB(49));
  float* ctx   = Q;   // Q dead after attn_kernel; ctx written afterwards

  dim3 g(8, 64), blk(256);
  gemm_bt<<<g, blk, 0, stream>>>(query, Wq, bq, 0.125f, Q);
  gemm_bt<<<g, blk, 0, stream>>>(key,   Wk, bk, 1.0f,   K);
  gemm_bt<<<g, blk, 0, stream>>>(value, Wv, bv, 1.0f,   V);

  transposeK_kernel<<<512, 256, 0, stream>>>(K, Kt);

  mscore_kernel<<<16384, 256, 0, stream>>>(Q, K, idxs, Mbuf);
  topk_kernel<<<NBH, 256, 0, stream>>>(Mbuf, Mtop);
  meanv_part<<<256, 256, 0, stream>>>(V, vpart);
  meanv_final<<<8, 256, 0, stream>>>(vpart, mnV);
  attn_kernel<<<NBH * 8, 256, 0, stream>>>(Q, Kt, V, Mtop, upd);

  fillctx_kernel<<<4096, 256, 0, stream>>>(mnV, ctx);
  scatter_kernel<<<NBH * UP, 64, 0, stream>>>(upd, Mtop, ctx);

  gemm_bt<<<g, blk, 0, stream>>>(ctx, Wo, bo, 1.0f, out);
}